// Round 13
// baseline (965.184 us; speedup 1.0000x reference)
//
#include <hip/hip_runtime.h>
#include <hip/hip_bf16.h>

#define VOCAB 32000
#define EMBED 512
#define HIDDEN 1024
#define NB 8
#define NT 256
#define XH_ROWS 16

#define NCH 8      // independent chains (= batch)
#define NMEM 32    // blocks per chain
#define RCOLS 32   // hidden columns per block

typedef __attribute__((ext_vector_type(8))) short bf16x8;
typedef __attribute__((ext_vector_type(4))) float f32x4;
typedef __attribute__((ext_vector_type(4))) unsigned u32x4;

#define AS1 __attribute__((address_space(1)))
#define AS3 __attribute__((address_space(3)))

__device__ __forceinline__ unsigned short bf16_bits(float f) {
    __hip_bfloat16 b = __float2bfloat16(f);
    unsigned short s;
    __builtin_memcpy(&s, &b, 2);
    return s;
}
__device__ __forceinline__ float lo16f(unsigned u) { return __uint_as_float(u << 16); }
__device__ __forceinline__ float hi16f(unsigned u) { return __uint_as_float(u & 0xffff0000u); }

// XCD-local L2 fast load (sc0 = bypass L1, hit this XCD's L2)
__device__ __forceinline__ unsigned long long sc0_load64(const unsigned long long* p) {
    unsigned long long v;
    asm volatile("global_load_dwordx2 %0, %1, off sc0\n\ts_waitcnt vmcnt(0)"
                 : "=v"(v) : "v"(p) : "memory");
    return v;
}
__device__ __forceinline__ void sc0_load64x2(unsigned long long& a, unsigned long long& b,
                                             const unsigned long long* p0,
                                             const unsigned long long* p1) {
    asm volatile("global_load_dwordx2 %0, %2, off sc0\n\t"
                 "global_load_dwordx2 %1, %3, off sc0\n\t"
                 "s_waitcnt vmcnt(0)"
                 : "=&v"(a), "=&v"(b) : "v"(p0), "v"(p1) : "memory");
}

// ---------------- W_hy [HIDDEN][VOCAB] f32 -> Wt [VOCAB][HIDDEN] bf16 ----------------
__global__ __launch_bounds__(256) void k_transpose(const float* __restrict__ W,
                                                   __hip_bfloat16* __restrict__ Wt) {
    __shared__ float tile[32][33];
    const int n0 = blockIdx.x * 32;
    const int k0 = blockIdx.y * 32;
    const int c = threadIdx.x & 31;
    const int r0 = threadIdx.x >> 5;
#pragma unroll
    for (int rr = 0; rr < 4; ++rr) {
        const int r = r0 + rr * 8;
        tile[c][r] = W[(size_t)(k0 + r) * VOCAB + n0 + c];
    }
    __syncthreads();
#pragma unroll
    for (int rr = 0; rr < 4; ++rr) {
        const int n = r0 + rr * 8;
        Wt[(size_t)(n0 + n) * HIDDEN + k0 + c] = __float2bfloat16(tile[n][c]);
    }
}

// ---------------- xh = emb[x] @ W_xh + b_h  (fp32) ----------------
__global__ __launch_bounds__(256) void k_xh(const int* __restrict__ ids,
                                            const float* __restrict__ emb,
                                            const float* __restrict__ Wxh,
                                            const float* __restrict__ bh,
                                            float* __restrict__ xh) {
    __shared__ alignas(16) float embS[XH_ROWS][EMBED];
    __shared__ int idsS[XH_ROWS];
    const int tid = threadIdx.x;
    const int blk = blockIdx.x;
    if (tid < XH_ROWS) idsS[tid] = ids[blk * XH_ROWS + tid];
    __syncthreads();
    const float4* emb4 = (const float4*)emb;
#pragma unroll
    for (int rep = 0; rep < (XH_ROWS * EMBED / 4) / 256; ++rep) {
        const int lin = rep * 256 + tid;
        const int r = lin >> 7;
        const int e4 = lin & 127;
        *(float4*)&embS[r][e4 * 4] = emb4[(size_t)idsS[r] * (EMBED / 4) + e4];
    }
    __syncthreads();
    float4 acc[XH_ROWS] = {};
    const float4* W4 = (const float4*)Wxh;
    for (int e = 0; e < EMBED; ++e) {
        const float4 w = W4[(size_t)e * (HIDDEN / 4) + tid];
#pragma unroll
        for (int r = 0; r < XH_ROWS; ++r) {
            const float ev = embS[r][e];
            acc[r].x += ev * w.x; acc[r].y += ev * w.y;
            acc[r].z += ev * w.z; acc[r].w += ev * w.w;
        }
    }
    const float4 bv = ((const float4*)bh)[tid];
#pragma unroll
    for (int r = 0; r < XH_ROWS; ++r) {
        float4 o;
        o.x = acc[r].x + bv.x; o.y = acc[r].y + bv.y;
        o.z = acc[r].z + bv.z; o.w = acc[r].w + bv.w;
        ((float4*)xh)[(size_t)(blk * XH_ROWS + r) * (HIDDEN / 4) + tid] = o;
    }
}

// ---------------- persistent recurrence: XCD-bound chains, dual-copy u64 exchange ----------------
// chain = physical XCD (s_getreg hwreg 20); member = per-XCD atomic slot. All members of
// a chain share one XCD -> plain stores + sc0 loads meet in the XCD-local L2 (fast).
// Agent-scope copy (hxA) is always maintained; polls alternate fast/agent after 3 tries
// -> correct under ANY placement (incl. overflow members on a foreign XCD).
// Overflow (XCD got >32 blocks): wait for all 256 check-ins (all blocks co-resident,
// increments precede waits -> no deadlock), then fill holes deterministically.
// Token-in-data u64 protocol unchanged (deadlock-free + replay-safe).
__global__ __launch_bounds__(256, 1) void k_rec(const float* __restrict__ Whh,
                                                const float* __restrict__ xh,
                                                unsigned long long* __restrict__ hxA,
                                                unsigned long long* __restrict__ hxF,
                                                unsigned* __restrict__ ctr,
                                                __hip_bfloat16* __restrict__ hs) {
    __shared__ float xhS[NT * RCOLS];      // 32 KB, [t][col]
    __shared__ float hS[16 * 68];          // padded: elem e -> e + 4*(e>>6); bank = ii + 4*part
    __shared__ float red[16 * 33];
    __shared__ int sChain, sMember;
    const int tid = threadIdx.x;

    if (tid == 0) {
        unsigned xcd;
        asm volatile("s_getreg_b32 %0, hwreg(20, 0, 4)" : "=s"(xcd));
        xcd &= 7u;
        const unsigned slot = __hip_atomic_fetch_add(&ctr[xcd], 1u, __ATOMIC_RELAXED,
                                                     __HIP_MEMORY_SCOPE_AGENT);
        __hip_atomic_fetch_add(&ctr[8], 1u, __ATOMIC_ACQ_REL, __HIP_MEMORY_SCOPE_AGENT);
        int chain, member;
        if (slot < (unsigned)NMEM) {
            chain = (int)xcd; member = (int)slot;
        } else {
            while (__hip_atomic_load(&ctr[8], __ATOMIC_ACQUIRE, __HIP_MEMORY_SCOPE_AGENT) < 256u)
                __builtin_amdgcn_s_sleep(2);
            const unsigned oidx = __hip_atomic_fetch_add(&ctr[9], 1u, __ATOMIC_RELAXED,
                                                         __HIP_MEMORY_SCOPE_AGENT);
            int k = -1; chain = 0; member = 0;
            for (int c2 = 0; c2 < 8 && k < (int)oidx; ++c2) {
                unsigned cf = __hip_atomic_load(&ctr[c2], __ATOMIC_RELAXED, __HIP_MEMORY_SCOPE_AGENT);
                int filled = cf < (unsigned)NMEM ? (int)cf : NMEM;
                for (int m2 = filled; m2 < NMEM && k < (int)oidx; ++m2) {
                    ++k;
                    if (k == (int)oidx) { chain = c2; member = m2; }
                }
            }
        }
        sChain = chain; sMember = member;
    }
    __syncthreads();
    const int c = sChain;
    const int m = sMember;
    const int j0 = m * RCOLS;
    unsigned long long* hxcA = hxA + (size_t)c * 1024;   // [2][512] u64 words
    unsigned long long* hxcF = hxF + (size_t)c * 1024;

    // h_{-1} = 0 with token 0 lives in buf[1]; this member's 16 words, both copies
    if (tid < 16) {
        __hip_atomic_store(&hxcA[512 + m * 16 + tid], 0ull, __ATOMIC_RELAXED,
                           __HIP_MEMORY_SCOPE_AGENT);
        __hip_atomic_store(&hxcF[512 + m * 16 + tid], 0ull, __ATOMIC_RELAXED,
                           __HIP_MEMORY_SCOPE_WORKGROUP);
    }

    const int col2 = tid & 15;
    const int part = tid >> 4;

    // W slice into registers: thread (part,col2) covers rows part*64..+63,
    // cols {j0+2*col2, j0+2*col2+1}, packed 2 bf16 per u32.
    u32x4 wreg[16];
#pragma unroll
    for (int j = 0; j < 16; ++j) {
        u32x4 q;
#pragma unroll
        for (int e = 0; e < 4; ++e) {
            const int i = part * 64 + 4 * j + e;
            const float2 wv = *(const float2*)&Whh[(size_t)i * HIDDEN + j0 + 2 * col2];
            q[e] = (unsigned)bf16_bits(wv.x) | ((unsigned)bf16_bits(wv.y) << 16);
        }
        wreg[j] = q;
    }
    for (int idx = tid; idx < NT * RCOLS; idx += 256) {
        const int t = idx >> 5;
        const int col = idx & 31;
        xhS[idx] = xh[(size_t)(c * NT + t) * HIDDEN + j0 + col];
    }
    __syncthreads();

    const f32x4* hv4 = (const f32x4*)&hS[part * 68];
    const int w0 = tid;
    const int w1 = tid + 256;
    const int pe0 = 2 * tid + 4 * (tid >> 5);

    for (int t = 0; t < NT; ++t) {
        const int roff = ((t + 1) & 1) * 512;   // holds h_{t-1}, tokens == t
        const int woff = (t & 1) * 512;         // we write h_t, token t+1
        const unsigned long long tok = (unsigned long long)(unsigned)t;
        const unsigned long long* pF0 = hxcF + roff + w0;
        const unsigned long long* pF1 = hxcF + roff + w1;
        const unsigned long long* pA0 = hxcA + roff + w0;
        const unsigned long long* pA1 = hxcA + roff + w1;
        unsigned long long a, b;
        sc0_load64x2(a, b, pF0, pF1);
        int tries = 0;
        while (((a & 0xffffull) != tok) | ((b & 0xffffull) != tok)) {
            ++tries;
            const bool useFast = (tries <= 3) | ((tries & 1) != 0);
            if ((a & 0xffffull) != tok)
                a = useFast ? sc0_load64(pF0)
                            : __hip_atomic_load(pA0, __ATOMIC_RELAXED, __HIP_MEMORY_SCOPE_AGENT);
            if ((b & 0xffffull) != tok)
                b = useFast ? sc0_load64(pF1)
                            : __hip_atomic_load(pA1, __ATOMIC_RELAXED, __HIP_MEMORY_SCOPE_AGENT);
        }
        *(float2*)&hS[pe0] = make_float2(__uint_as_float(((unsigned)(a >> 16) & 0xffffu) << 16),
                                         __uint_as_float(((unsigned)(a >> 32) & 0xffffu) << 16));
        *(float2*)&hS[pe0 + 544] = make_float2(__uint_as_float(((unsigned)(b >> 16) & 0xffffu) << 16),
                                               __uint_as_float(((unsigned)(b >> 32) & 0xffffu) << 16));
        __syncthreads();
        float a0 = 0.f, a1 = 0.f;
#pragma unroll
        for (int j = 0; j < 16; ++j) {
            const u32x4 w4 = wreg[j];
            const f32x4 h4 = hv4[j];
            a0 = fmaf(lo16f(w4.x), h4.x, a0); a1 = fmaf(hi16f(w4.x), h4.x, a1);
            a0 = fmaf(lo16f(w4.y), h4.y, a0); a1 = fmaf(hi16f(w4.y), h4.y, a1);
            a0 = fmaf(lo16f(w4.z), h4.z, a0); a1 = fmaf(hi16f(w4.z), h4.z, a1);
            a0 = fmaf(lo16f(w4.w), h4.w, a0); a1 = fmaf(hi16f(w4.w), h4.w, a1);
        }
        red[part * 33 + 2 * col2]     = a0;
        red[part * 33 + 2 * col2 + 1] = a1;
        __syncthreads();
        if (tid < RCOLS) {
            float s = 0.f;
#pragma unroll
            for (int p = 0; p < 16; ++p) s += red[p * 33 + tid];
            const float v = tanhf(xhS[t * RCOLS + tid] + s);
            const unsigned hb = (unsigned)bf16_bits(v);
            ((unsigned short*)hs)[(size_t)(c * NT + t) * HIDDEN + j0 + tid] = (unsigned short)hb;
            const unsigned pb = (unsigned)__shfl_xor((int)hb, 1, 64);
            if ((tid & 1) == 0) {
                const unsigned long long wv = (unsigned long long)(unsigned)(t + 1)
                                            | ((unsigned long long)hb << 16)
                                            | ((unsigned long long)pb << 32);
                __hip_atomic_store(&hxcA[woff + m * 16 + (tid >> 1)], wv, __ATOMIC_RELAXED,
                                   __HIP_MEMORY_SCOPE_AGENT);
                __hip_atomic_store(&hxcF[woff + m * 16 + (tid >> 1)], wv, __ATOMIC_RELAXED,
                                   __HIP_MEMORY_SCOPE_WORKGROUP);
            }
        }
    }
}

// ---------------- y = hs @ Wt^T + b_y : 256x256 tile, counted-vmcnt pipeline ----------------
// (unchanged from round 12)
__global__ __launch_bounds__(512, 2) void k_proj(const unsigned short* __restrict__ A,   // [2048][1024]
                                                 const unsigned short* __restrict__ Bt,  // [32000][1024]
                                                 const float* __restrict__ by,
                                                 float* __restrict__ C) {
    __shared__ unsigned short LDS[4][16384];   // [buf*2+mat][256*64] bf16
    const int tid = threadIdx.x;
    const int wid = tid >> 6;
    const int lane = tid & 63;
    const int lin = blockIdx.x;
    const int swz = (lin & 7) * 125 + (lin >> 3);
    const int mt = swz & 7, nt = swz >> 3;
    const int m0 = mt * 256, n0 = nt * 256;
    const int wr = wid >> 2, wc = wid & 3;
    const int fr = lane & 15, fq = lane >> 4;
    const int srow = tid >> 3;
    const int sslot = tid & 7;

    f32x4 acc[8][4] = {};

#define STAGE(kt, bf)                                                                     \
    {                                                                                     \
        const unsigned short* Ag = A + (size_t)m0 * HIDDEN + (size_t)(kt) * 64;           \
        const unsigned short* Bg = Bt + (size_t)n0 * HIDDEN + (size_t)(kt) * 64;          \
        _Pragma("unroll")                                                                 \
        for (int j = 0; j < 4; ++j) {                                                     \
            const int r = j * 64 + srow;                                                  \
            const int ls = ((sslot ^ (r & 7)) * 8);                                       \
            __builtin_amdgcn_global_load_lds(                                             \
                (const AS1 unsigned*)(Ag + (size_t)r * HIDDEN + ls),                      \
                (AS3 unsigned*)(&LDS[(bf) * 2 + 0][j * 4096 + wid * 512]), 16, 0, 0);     \
        }                                                                                 \
        _Pragma("unroll")                                                                 \
        for (int j = 0; j < 4; ++j) {                                                     \
            const int r = j * 64 + srow;                                                  \
            const int ls = ((sslot ^ (r & 7)) * 8);                                       \
            __builtin_amdgcn_global_load_lds(                                             \
                (const AS1 unsigned*)(Bg + (size_t)r * HIDDEN + ls),                      \
                (AS3 unsigned*)(&LDS[(bf) * 2 + 1][j * 4096 + wid * 512]), 16, 0, 0);     \
        }                                                                                 \
    }

    STAGE(0, 0);
    STAGE(1, 1);

    int cur = 0;
    for (int kt = 0; kt < 16; ++kt) {
        if (kt < 15) { asm volatile("s_waitcnt vmcnt(8)" ::: "memory"); }
        else         { asm volatile("s_waitcnt vmcnt(0)" ::: "memory"); }
        __builtin_amdgcn_s_barrier();

        const unsigned short* Ab = &LDS[cur * 2 + 0][0];
        const unsigned short* Bb = &LDS[cur * 2 + 1][0];
        bf16x8 af[8][2], bg[4][2];
#pragma unroll
        for (int mi = 0; mi < 8; ++mi) {
            const int ra = wr * 128 + mi * 16 + fr;
#pragma unroll
            for (int ks = 0; ks < 2; ++ks)
                af[mi][ks] = *(const bf16x8*)&Ab[ra * 64 + (((ks * 4 + fq) ^ (fr & 7)) * 8)];
        }
#pragma unroll
        for (int ni = 0; ni < 4; ++ni) {
            const int rb = wc * 64 + ni * 16 + fr;
#pragma unroll
            for (int ks = 0; ks < 2; ++ks)
                bg[ni][ks] = *(const bf16x8*)&Bb[rb * 64 + (((ks * 4 + fq) ^ (fr & 7)) * 8)];
        }
        asm volatile("s_waitcnt lgkmcnt(0)" ::: "memory");
        __builtin_amdgcn_sched_barrier(0);
        __builtin_amdgcn_s_barrier();

        if (kt < 14) STAGE(kt + 2, cur);

        __builtin_amdgcn_s_setprio(1);
#pragma unroll
        for (int mi = 0; mi < 8; ++mi)
#pragma unroll
            for (int ni = 0; ni < 4; ++ni) {
                acc[mi][ni] = __builtin_amdgcn_mfma_f32_16x16x32_bf16(af[mi][0], bg[ni][0], acc[mi][ni], 0, 0, 0);
                acc[mi][ni] = __builtin_amdgcn_mfma_f32_16x16x32_bf16(af[mi][1], bg[ni][1], acc[mi][ni], 0, 0, 0);
            }
        __builtin_amdgcn_s_setprio(0);
        cur ^= 1;
    }
#undef STAGE

#pragma unroll
    for (int ni = 0; ni < 4; ++ni) {
        const int col = n0 + wc * 64 + ni * 16 + fr;
        const float bias = by[col];
#pragma unroll
        for (int mi = 0; mi < 8; ++mi) {
            const int row = m0 + wr * 128 + mi * 16 + fq * 4;
            float* cp = C + (size_t)row * VOCAB + col;
            cp[0]                 = acc[mi][ni][0] + bias;
            cp[(size_t)VOCAB]     = acc[mi][ni][1] + bias;
            cp[(size_t)2 * VOCAB] = acc[mi][ni][2] + bias;
            cp[(size_t)3 * VOCAB] = acc[mi][ni][3] + bias;
        }
    }
}

extern "C" void kernel_launch(void* const* d_in, const int* in_sizes, int n_in,
                              void* d_out, int out_size, void* d_ws, size_t ws_size,
                              hipStream_t stream) {
    const int*   x   = (const int*)d_in[0];
    const float* emb = (const float*)d_in[1];
    const float* Wxh = (const float*)d_in[2];
    const float* Whh = (const float*)d_in[3];
    const float* bh  = (const float*)d_in[4];
    const float* Why = (const float*)d_in[5];
    const float* by  = (const float*)d_in[6];
    float* y = (float*)d_out;

    char* ws = (char*)d_ws;
    // layout: xh (8MB) | hxA (64KB) | hxF (64KB) | ctr (256B) | hs bf16 (4MB) | Wt bf16 (62.5MB)
    const size_t off_xh  = 0;
    const size_t off_hxa = off_xh + (size_t)NB * NT * HIDDEN * 4;
    const size_t off_hxf = off_hxa + (size_t)NCH * 2 * 512 * 8;
    const size_t off_ctr = off_hxf + (size_t)NCH * 2 * 512 * 8;
    const size_t off_hs  = off_ctr + 256;
    const size_t off_wt  = off_hs + (size_t)NB * NT * HIDDEN * 2;
    const size_t need    = off_wt + (size_t)VOCAB * HIDDEN * 2;
    if (ws_size < need) return;

    float* xh = (float*)(ws + off_xh);
    unsigned long long* hxA = (unsigned long long*)(ws + off_hxa);
    unsigned long long* hxF = (unsigned long long*)(ws + off_hxf);
    unsigned* ctr = (unsigned*)(ws + off_ctr);
    __hip_bfloat16* hs = (__hip_bfloat16*)(ws + off_hs);
    __hip_bfloat16* Wt = (__hip_bfloat16*)(ws + off_wt);

    hipMemsetAsync(ctr, 0, 256, stream);
    k_xh<<<dim3((NB * NT) / XH_ROWS), 256, 0, stream>>>(x, emb, Wxh, bh, xh);
    k_transpose<<<dim3(VOCAB / 32, HIDDEN / 32), 256, 0, stream>>>(Why, Wt);
    k_rec<<<dim3(NCH * NMEM), 256, 0, stream>>>(Whh, xh, hxA, hxF, ctr, hs);
    k_proj<<<dim3((2048 / 256) * (VOCAB / 256)), 512, 0, stream>>>((const unsigned short*)hs,
                                                                   (const unsigned short*)Wt, by, y);
}

// Round 14
// 798.785 us; speedup vs baseline: 1.2083x; 1.2083x over previous
//
#include <hip/hip_runtime.h>
#include <hip/hip_bf16.h>

#define VOCAB 32000
#define EMBED 512
#define HIDDEN 1024
#define NB 8
#define NT 256
#define XH_ROWS 16

#define NCH 8        // independent chains (= batch)
#define NMEM 32      // blocks per chain
#define RCOLS 32     // hidden columns per block
#define NBLK_REC 256
#define NBLK_TR 64
#define TILES_PER_TR 500   // (VOCAB/32)*(HIDDEN/32) / NBLK_TR = 32000/64

typedef __attribute__((ext_vector_type(8))) short bf16x8;
typedef __attribute__((ext_vector_type(4))) float f32x4;
typedef __attribute__((ext_vector_type(4))) unsigned u32x4;

#define AS1 __attribute__((address_space(1)))
#define AS3 __attribute__((address_space(3)))

__device__ __forceinline__ unsigned short bf16_bits(float f) {
    __hip_bfloat16 b = __float2bfloat16(f);
    unsigned short s;
    __builtin_memcpy(&s, &b, 2);
    return s;
}
__device__ __forceinline__ float lo16f(unsigned u) { return __uint_as_float(u << 16); }
__device__ __forceinline__ float hi16f(unsigned u) { return __uint_as_float(u & 0xffff0000u); }

// ---------------- xh = emb[x] @ W_xh + b_h  (fp32) ----------------
__global__ __launch_bounds__(256) void k_xh(const int* __restrict__ ids,
                                            const float* __restrict__ emb,
                                            const float* __restrict__ Wxh,
                                            const float* __restrict__ bh,
                                            float* __restrict__ xh) {
    __shared__ alignas(16) float embS[XH_ROWS][EMBED];
    __shared__ int idsS[XH_ROWS];
    const int tid = threadIdx.x;
    const int blk = blockIdx.x;
    if (tid < XH_ROWS) idsS[tid] = ids[blk * XH_ROWS + tid];
    __syncthreads();
    const float4* emb4 = (const float4*)emb;
#pragma unroll
    for (int rep = 0; rep < (XH_ROWS * EMBED / 4) / 256; ++rep) {
        const int lin = rep * 256 + tid;
        const int r = lin >> 7;
        const int e4 = lin & 127;
        *(float4*)&embS[r][e4 * 4] = emb4[(size_t)idsS[r] * (EMBED / 4) + e4];
    }
    __syncthreads();
    float4 acc[XH_ROWS] = {};
    const float4* W4 = (const float4*)Wxh;
    for (int e = 0; e < EMBED; ++e) {
        const float4 w = W4[(size_t)e * (HIDDEN / 4) + tid];
#pragma unroll
        for (int r = 0; r < XH_ROWS; ++r) {
            const float ev = embS[r][e];
            acc[r].x += ev * w.x; acc[r].y += ev * w.y;
            acc[r].z += ev * w.z; acc[r].w += ev * w.w;
        }
    }
    const float4 bv = ((const float4*)bh)[tid];
#pragma unroll
    for (int r = 0; r < XH_ROWS; ++r) {
        float4 o;
        o.x = acc[r].x + bv.x; o.y = acc[r].y + bv.y;
        o.z = acc[r].z + bv.z; o.w = acc[r].w + bv.w;
        ((float4*)xh)[(size_t)(blk * XH_ROWS + r) * (HIDDEN / 4) + tid] = o;
    }
}

// ---------------- fused persistent recurrence + W_hy transpose ----------------
// Blocks 0..255: round-12 recurrence verbatim (u64 token-in-data, W in registers,
//   agent-scope atomics only -- the measured-fastest protocol; sc0 fast path
//   refuted twice, r9/r13).
// Blocks 256..319: W_hy [HIDDEN][VOCAB] f32 -> Wt [VOCAB][HIDDEN] bf16, 500 tiles
//   each, hidden under the latency-bound recurrence (chip ~90% idle there).
// Co-residency: 320 blocks x 39KB LDS fits 4/CU -> all recurrence blocks resident.
__global__ __launch_bounds__(256, 1) void k_fused(const float* __restrict__ Whh,
                                                  const float* __restrict__ xh,
                                                  unsigned long long* __restrict__ hx,
                                                  __hip_bfloat16* __restrict__ hs,
                                                  const float* __restrict__ Why,
                                                  __hip_bfloat16* __restrict__ Wt) {
    __shared__ float xhS[NT * RCOLS];      // 32 KB, [t][col]; transpose role reuses head
    __shared__ float hS[16 * 68];
    __shared__ float red[16 * 33];
    const int tid = threadIdx.x;
    const int bid = blockIdx.x;

    if (bid >= NBLK_REC) {
        // ---- transpose role ----
        const int tb = bid - NBLK_REC;
        float (*tile)[33] = (float(*)[33])xhS;   // 4.2 KB overlay
        const int cc = tid & 31;
        const int r0 = tid >> 5;
        for (int i = 0; i < TILES_PER_TR; ++i) {
            const int g = tb * TILES_PER_TR + i;
            const int n0 = (g % 1000) * 32;
            const int k0 = (g / 1000) * 32;
            __syncthreads();
#pragma unroll
            for (int rr = 0; rr < 4; ++rr) {
                const int r = r0 + rr * 8;
                tile[cc][r] = Why[(size_t)(k0 + r) * VOCAB + n0 + cc];
            }
            __syncthreads();
#pragma unroll
            for (int rr = 0; rr < 4; ++rr) {
                const int n = r0 + rr * 8;
                Wt[(size_t)(n0 + n) * HIDDEN + k0 + cc] = __float2bfloat16(tile[n][cc]);
            }
        }
        return;
    }

    // ---- recurrence role (round-12 verbatim) ----
    const int c = bid & (NCH - 1);
    const int m = bid >> 3;
    const int j0 = m * RCOLS;
    unsigned long long* hxc = hx + (size_t)c * 1024;

    if (tid < 16)
        __hip_atomic_store(&hxc[512 + m * 16 + tid], 0ull, __ATOMIC_RELAXED,
                           __HIP_MEMORY_SCOPE_AGENT);

    const int col2 = tid & 15;
    const int part = tid >> 4;

    u32x4 wreg[16];
#pragma unroll
    for (int j = 0; j < 16; ++j) {
        u32x4 q;
#pragma unroll
        for (int e = 0; e < 4; ++e) {
            const int i = part * 64 + 4 * j + e;
            const float2 wv = *(const float2*)&Whh[(size_t)i * HIDDEN + j0 + 2 * col2];
            q[e] = (unsigned)bf16_bits(wv.x) | ((unsigned)bf16_bits(wv.y) << 16);
        }
        wreg[j] = q;
    }
    for (int idx = tid; idx < NT * RCOLS; idx += 256) {
        const int t = idx >> 5;
        const int col = idx & 31;
        xhS[idx] = xh[(size_t)(c * NT + t) * HIDDEN + j0 + col];
    }
    __syncthreads();

    const f32x4* hv4 = (const f32x4*)&hS[part * 68];
    const int w0 = tid;
    const int w1 = tid + 256;
    const int pe0 = 2 * tid + 4 * (tid >> 5);

    for (int t = 0; t < NT; ++t) {
        unsigned long long* rbuf = hxc + ((t + 1) & 1) * 512;
        unsigned long long* wbuf = hxc + (t & 1) * 512;
        const unsigned long long tok = (unsigned long long)(unsigned)t;
        unsigned long long a = __hip_atomic_load(&rbuf[w0], __ATOMIC_RELAXED, __HIP_MEMORY_SCOPE_AGENT);
        unsigned long long b = __hip_atomic_load(&rbuf[w1], __ATOMIC_RELAXED, __HIP_MEMORY_SCOPE_AGENT);
        while (((a & 0xffffull) != tok) | ((b & 0xffffull) != tok)) {
            __builtin_amdgcn_s_sleep(1);
            if ((a & 0xffffull) != tok)
                a = __hip_atomic_load(&rbuf[w0], __ATOMIC_RELAXED, __HIP_MEMORY_SCOPE_AGENT);
            if ((b & 0xffffull) != tok)
                b = __hip_atomic_load(&rbuf[w1], __ATOMIC_RELAXED, __HIP_MEMORY_SCOPE_AGENT);
        }
        *(float2*)&hS[pe0] = make_float2(__uint_as_float(((unsigned)(a >> 16) & 0xffffu) << 16),
                                         __uint_as_float(((unsigned)(a >> 32) & 0xffffu) << 16));
        *(float2*)&hS[pe0 + 544] = make_float2(__uint_as_float(((unsigned)(b >> 16) & 0xffffu) << 16),
                                               __uint_as_float(((unsigned)(b >> 32) & 0xffffu) << 16));
        __syncthreads();
        float a0 = 0.f, a1 = 0.f;
#pragma unroll
        for (int j = 0; j < 16; ++j) {
            const u32x4 w4 = wreg[j];
            const f32x4 h4 = hv4[j];
            a0 = fmaf(lo16f(w4.x), h4.x, a0); a1 = fmaf(hi16f(w4.x), h4.x, a1);
            a0 = fmaf(lo16f(w4.y), h4.y, a0); a1 = fmaf(hi16f(w4.y), h4.y, a1);
            a0 = fmaf(lo16f(w4.z), h4.z, a0); a1 = fmaf(hi16f(w4.z), h4.z, a1);
            a0 = fmaf(lo16f(w4.w), h4.w, a0); a1 = fmaf(hi16f(w4.w), h4.w, a1);
        }
        red[part * 33 + 2 * col2]     = a0;
        red[part * 33 + 2 * col2 + 1] = a1;
        __syncthreads();
        if (tid < RCOLS) {
            float s = 0.f;
#pragma unroll
            for (int p = 0; p < 16; ++p) s += red[p * 33 + tid];
            const float v = tanhf(xhS[t * RCOLS + tid] + s);
            const unsigned hb = (unsigned)bf16_bits(v);
            ((unsigned short*)hs)[(size_t)(c * NT + t) * HIDDEN + j0 + tid] = (unsigned short)hb;
            const unsigned pb = (unsigned)__shfl_xor((int)hb, 1, 64);
            if ((tid & 1) == 0) {
                const unsigned long long wv = (unsigned long long)(unsigned)(t + 1)
                                            | ((unsigned long long)hb << 16)
                                            | ((unsigned long long)pb << 32);
                __hip_atomic_store(&wbuf[m * 16 + (tid >> 1)], wv, __ATOMIC_RELAXED,
                                   __HIP_MEMORY_SCOPE_AGENT);
            }
        }
    }
}

// ---------------- y = hs @ Wt^T + b_y : 256x256 tile, counted-vmcnt pipeline ----------------
// (unchanged from round 12: linear-dest global_load_lds + XOR-swizzled reads,
//  raw s_barrier, vmcnt(8) cross-barrier prefetch, setprio around MFMA)
__global__ __launch_bounds__(512, 2) void k_proj(const unsigned short* __restrict__ A,   // [2048][1024]
                                                 const unsigned short* __restrict__ Bt,  // [32000][1024]
                                                 const float* __restrict__ by,
                                                 float* __restrict__ C) {
    __shared__ unsigned short LDS[4][16384];   // [buf*2+mat][256*64] bf16
    const int tid = threadIdx.x;
    const int wid = tid >> 6;
    const int lane = tid & 63;
    const int lin = blockIdx.x;
    const int swz = (lin & 7) * 125 + (lin >> 3);
    const int mt = swz & 7, nt = swz >> 3;
    const int m0 = mt * 256, n0 = nt * 256;
    const int wr = wid >> 2, wc = wid & 3;
    const int fr = lane & 15, fq = lane >> 4;
    const int srow = tid >> 3;
    const int sslot = tid & 7;

    f32x4 acc[8][4] = {};

#define STAGE(kt, bf)                                                                     \
    {                                                                                     \
        const unsigned short* Ag = A + (size_t)m0 * HIDDEN + (size_t)(kt) * 64;           \
        const unsigned short* Bg = Bt + (size_t)n0 * HIDDEN + (size_t)(kt) * 64;          \
        _Pragma("unroll")                                                                 \
        for (int j = 0; j < 4; ++j) {                                                     \
            const int r = j * 64 + srow;                                                  \
            const int ls = ((sslot ^ (r & 7)) * 8);                                       \
            __builtin_amdgcn_global_load_lds(                                             \
                (const AS1 unsigned*)(Ag + (size_t)r * HIDDEN + ls),                      \
                (AS3 unsigned*)(&LDS[(bf) * 2 + 0][j * 4096 + wid * 512]), 16, 0, 0);     \
        }                                                                                 \
        _Pragma("unroll")                                                                 \
        for (int j = 0; j < 4; ++j) {                                                     \
            const int r = j * 64 + srow;                                                  \
            const int ls = ((sslot ^ (r & 7)) * 8);                                       \
            __builtin_amdgcn_global_load_lds(                                             \
                (const AS1 unsigned*)(Bg + (size_t)r * HIDDEN + ls),                      \
                (AS3 unsigned*)(&LDS[(bf) * 2 + 1][j * 4096 + wid * 512]), 16, 0, 0);     \
        }                                                                                 \
    }

    STAGE(0, 0);
    STAGE(1, 1);

    int cur = 0;
    for (int kt = 0; kt < 16; ++kt) {
        if (kt < 15) { asm volatile("s_waitcnt vmcnt(8)" ::: "memory"); }
        else         { asm volatile("s_waitcnt vmcnt(0)" ::: "memory"); }
        __builtin_amdgcn_s_barrier();

        const unsigned short* Ab = &LDS[cur * 2 + 0][0];
        const unsigned short* Bb = &LDS[cur * 2 + 1][0];
        bf16x8 af[8][2], bg[4][2];
#pragma unroll
        for (int mi = 0; mi < 8; ++mi) {
            const int ra = wr * 128 + mi * 16 + fr;
#pragma unroll
            for (int ks = 0; ks < 2; ++ks)
                af[mi][ks] = *(const bf16x8*)&Ab[ra * 64 + (((ks * 4 + fq) ^ (fr & 7)) * 8)];
        }
#pragma unroll
        for (int ni = 0; ni < 4; ++ni) {
            const int rb = wc * 64 + ni * 16 + fr;
#pragma unroll
            for (int ks = 0; ks < 2; ++ks)
                bg[ni][ks] = *(const bf16x8*)&Bb[rb * 64 + (((ks * 4 + fq) ^ (fr & 7)) * 8)];
        }
        asm volatile("s_waitcnt lgkmcnt(0)" ::: "memory");
        __builtin_amdgcn_sched_barrier(0);
        __builtin_amdgcn_s_barrier();

        if (kt < 14) STAGE(kt + 2, cur);

        __builtin_amdgcn_s_setprio(1);
#pragma unroll
        for (int mi = 0; mi < 8; ++mi)
#pragma unroll
            for (int ni = 0; ni < 4; ++ni) {
                acc[mi][ni] = __builtin_amdgcn_mfma_f32_16x16x32_bf16(af[mi][0], bg[ni][0], acc[mi][ni], 0, 0, 0);
                acc[mi][ni] = __builtin_amdgcn_mfma_f32_16x16x32_bf16(af[mi][1], bg[ni][1], acc[mi][ni], 0, 0, 0);
            }
        __builtin_amdgcn_s_setprio(0);
        cur ^= 1;
    }
#undef STAGE

#pragma unroll
    for (int ni = 0; ni < 4; ++ni) {
        const int col = n0 + wc * 64 + ni * 16 + fr;
        const float bias = by[col];
#pragma unroll
        for (int mi = 0; mi < 8; ++mi) {
            const int row = m0 + wr * 128 + mi * 16 + fq * 4;
            float* cp = C + (size_t)row * VOCAB + col;
            cp[0]                 = acc[mi][ni][0] + bias;
            cp[(size_t)VOCAB]     = acc[mi][ni][1] + bias;
            cp[(size_t)2 * VOCAB] = acc[mi][ni][2] + bias;
            cp[(size_t)3 * VOCAB] = acc[mi][ni][3] + bias;
        }
    }
}

extern "C" void kernel_launch(void* const* d_in, const int* in_sizes, int n_in,
                              void* d_out, int out_size, void* d_ws, size_t ws_size,
                              hipStream_t stream) {
    const int*   x   = (const int*)d_in[0];
    const float* emb = (const float*)d_in[1];
    const float* Wxh = (const float*)d_in[2];
    const float* Whh = (const float*)d_in[3];
    const float* bh  = (const float*)d_in[4];
    const float* Why = (const float*)d_in[5];
    const float* by  = (const float*)d_in[6];
    float* y = (float*)d_out;

    char* ws = (char*)d_ws;
    // layout: xh (8 MB) | hx u64[8][2][512] (64 KB) | hs bf16 (4 MB) | Wt bf16 (62.5 MB)
    const size_t off_xh = 0;
    const size_t off_hx = off_xh + (size_t)NB * NT * HIDDEN * 4;
    const size_t off_hs = off_hx + (size_t)NCH * 2 * 512 * 8;
    const size_t off_wt = off_hs + (size_t)NB * NT * HIDDEN * 2;
    const size_t need   = off_wt + (size_t)VOCAB * HIDDEN * 2;
    if (ws_size < need) return;

    float* xh = (float*)(ws + off_xh);
    unsigned long long* hx = (unsigned long long*)(ws + off_hx);
    __hip_bfloat16* hs = (__hip_bfloat16*)(ws + off_hs);
    __hip_bfloat16* Wt = (__hip_bfloat16*)(ws + off_wt);

    k_xh<<<dim3((NB * NT) / XH_ROWS), 256, 0, stream>>>(x, emb, Wxh, bh, xh);
    k_fused<<<dim3(NBLK_REC + NBLK_TR), 256, 0, stream>>>(Whh, xh, hx, hs, Why, Wt);
    k_proj<<<dim3((2048 / 256) * (VOCAB / 256)), 512, 0, stream>>>((const unsigned short*)hs,
                                                                   (const unsigned short*)Wt, by, y);
}

// Round 15
// 793.427 us; speedup vs baseline: 1.2165x; 1.0068x over previous
//
#include <hip/hip_runtime.h>
#include <hip/hip_bf16.h>

#define VOCAB 32000
#define EMBED 512
#define HIDDEN 1024
#define NB 8
#define NT 256
#define XH_ROWS 16

#define NCH 8        // independent chains (= batch)
#define NMEM 32      // blocks per chain
#define RCOLS 32     // hidden columns per block
#define NBLK_REC 256
#define NBLK_TR 128
#define TILES_PER_TR 250   // 32000 tiles / 128 blocks

typedef __attribute__((ext_vector_type(8))) short bf16x8;
typedef __attribute__((ext_vector_type(4))) float f32x4;
typedef __attribute__((ext_vector_type(4))) unsigned u32x4;

#define AS1 __attribute__((address_space(1)))
#define AS3 __attribute__((address_space(3)))

__device__ __forceinline__ unsigned short bf16_bits(float f) {
    __hip_bfloat16 b = __float2bfloat16(f);
    unsigned short s;
    __builtin_memcpy(&s, &b, 2);
    return s;
}
__device__ __forceinline__ float lo16f(unsigned u) { return __uint_as_float(u << 16); }
__device__ __forceinline__ float hi16f(unsigned u) { return __uint_as_float(u & 0xffff0000u); }

// ---------------- xh = emb[x] @ W_xh + b_h  (fp32) ----------------
__global__ __launch_bounds__(256) void k_xh(const int* __restrict__ ids,
                                            const float* __restrict__ emb,
                                            const float* __restrict__ Wxh,
                                            const float* __restrict__ bh,
                                            float* __restrict__ xh) {
    __shared__ alignas(16) float embS[XH_ROWS][EMBED];
    __shared__ int idsS[XH_ROWS];
    const int tid = threadIdx.x;
    const int blk = blockIdx.x;
    if (tid < XH_ROWS) idsS[tid] = ids[blk * XH_ROWS + tid];
    __syncthreads();
    const float4* emb4 = (const float4*)emb;
#pragma unroll
    for (int rep = 0; rep < (XH_ROWS * EMBED / 4) / 256; ++rep) {
        const int lin = rep * 256 + tid;
        const int r = lin >> 7;
        const int e4 = lin & 127;
        *(float4*)&embS[r][e4 * 4] = emb4[(size_t)idsS[r] * (EMBED / 4) + e4];
    }
    __syncthreads();
    float4 acc[XH_ROWS] = {};
    const float4* W4 = (const float4*)Wxh;
    for (int e = 0; e < EMBED; ++e) {
        const float4 w = W4[(size_t)e * (HIDDEN / 4) + tid];
#pragma unroll
        for (int r = 0; r < XH_ROWS; ++r) {
            const float ev = embS[r][e];
            acc[r].x += ev * w.x; acc[r].y += ev * w.y;
            acc[r].z += ev * w.z; acc[r].w += ev * w.w;
        }
    }
    const float4 bv = ((const float4*)bh)[tid];
#pragma unroll
    for (int r = 0; r < XH_ROWS; ++r) {
        float4 o;
        o.x = acc[r].x + bv.x; o.y = acc[r].y + bv.y;
        o.z = acc[r].z + bv.z; o.w = acc[r].w + bv.w;
        ((float4*)xh)[(size_t)(blk * XH_ROWS + r) * (HIDDEN / 4) + tid] = o;
    }
}

// ---------------- fused persistent recurrence + W_hy transpose ----------------
// Blocks 0..255: round-12 recurrence verbatim (agent-atomic token-in-data; fastest
//   measured protocol). Blocks 256..383: transpose, 8 tiles per barrier round
//   (32 loads in flight/thread) -> ~32 rounds instead of 500: truly hidden.
__global__ __launch_bounds__(256, 1) void k_fused(const float* __restrict__ Whh,
                                                  const float* __restrict__ xh,
                                                  unsigned long long* __restrict__ hx,
                                                  __hip_bfloat16* __restrict__ hs,
                                                  const float* __restrict__ Why,
                                                  __hip_bfloat16* __restrict__ Wt) {
    __shared__ alignas(16) float smemF[9808];  // 39.2 KB, carved below
    float* xhS = smemF;                        // [NT*RCOLS] = 8192
    float* hS  = smemF + 8192;                 // [16*68]    = 1088
    float* red = smemF + 9280;                 // [16*33]    = 528
    const int tid = threadIdx.x;
    const int bid = blockIdx.x;

    if (bid >= NBLK_REC) {
        // ---- transpose role: 8 tiles (32x33 f32 each) per round ----
        const int tb = bid - NBLK_REC;
        const int cc = tid & 31;
        const int r0 = tid >> 5;
        const int tbase = tb * TILES_PER_TR;
        for (int rnd = 0; rnd < (TILES_PER_TR + 7) / 8; ++rnd) {
            const int base = rnd * 8;
            __syncthreads();
#pragma unroll
            for (int u = 0; u < 8; ++u) {
                const int i = base + u;
                if (i < TILES_PER_TR) {
                    const int g = tbase + i;
                    const int n0 = (g % 1000) * 32;
                    const int k0 = (g / 1000) * 32;
                    float* tile = smemF + u * 1056;
#pragma unroll
                    for (int rr = 0; rr < 4; ++rr) {
                        const int r = r0 + rr * 8;
                        tile[cc * 33 + r] = Why[(size_t)(k0 + r) * VOCAB + n0 + cc];
                    }
                }
            }
            __syncthreads();
#pragma unroll
            for (int u = 0; u < 8; ++u) {
                const int i = base + u;
                if (i < TILES_PER_TR) {
                    const int g = tbase + i;
                    const int n0 = (g % 1000) * 32;
                    const int k0 = (g / 1000) * 32;
                    float* tile = smemF + u * 1056;
#pragma unroll
                    for (int rr = 0; rr < 4; ++rr) {
                        const int n = r0 + rr * 8;
                        Wt[(size_t)(n0 + n) * HIDDEN + k0 + cc] = __float2bfloat16(tile[n * 33 + cc]);
                    }
                }
            }
        }
        return;
    }

    // ---- recurrence role (round-12 verbatim) ----
    const int c = bid & (NCH - 1);
    const int m = bid >> 3;
    const int j0 = m * RCOLS;
    unsigned long long* hxc = hx + (size_t)c * 1024;

    if (tid < 16)
        __hip_atomic_store(&hxc[512 + m * 16 + tid], 0ull, __ATOMIC_RELAXED,
                           __HIP_MEMORY_SCOPE_AGENT);

    const int col2 = tid & 15;
    const int part = tid >> 4;

    u32x4 wreg[16];
#pragma unroll
    for (int j = 0; j < 16; ++j) {
        u32x4 q;
#pragma unroll
        for (int e = 0; e < 4; ++e) {
            const int i = part * 64 + 4 * j + e;
            const float2 wv = *(const float2*)&Whh[(size_t)i * HIDDEN + j0 + 2 * col2];
            q[e] = (unsigned)bf16_bits(wv.x) | ((unsigned)bf16_bits(wv.y) << 16);
        }
        wreg[j] = q;
    }
    for (int idx = tid; idx < NT * RCOLS; idx += 256) {
        const int t = idx >> 5;
        const int col = idx & 31;
        xhS[idx] = xh[(size_t)(c * NT + t) * HIDDEN + j0 + col];
    }
    __syncthreads();

    const f32x4* hv4 = (const f32x4*)&hS[part * 68];
    const int w0 = tid;
    const int w1 = tid + 256;
    const int pe0 = 2 * tid + 4 * (tid >> 5);

    for (int t = 0; t < NT; ++t) {
        unsigned long long* rbuf = hxc + ((t + 1) & 1) * 512;
        unsigned long long* wbuf = hxc + (t & 1) * 512;
        const unsigned long long tok = (unsigned long long)(unsigned)t;
        unsigned long long a = __hip_atomic_load(&rbuf[w0], __ATOMIC_RELAXED, __HIP_MEMORY_SCOPE_AGENT);
        unsigned long long b = __hip_atomic_load(&rbuf[w1], __ATOMIC_RELAXED, __HIP_MEMORY_SCOPE_AGENT);
        while (((a & 0xffffull) != tok) | ((b & 0xffffull) != tok)) {
            __builtin_amdgcn_s_sleep(1);
            if ((a & 0xffffull) != tok)
                a = __hip_atomic_load(&rbuf[w0], __ATOMIC_RELAXED, __HIP_MEMORY_SCOPE_AGENT);
            if ((b & 0xffffull) != tok)
                b = __hip_atomic_load(&rbuf[w1], __ATOMIC_RELAXED, __HIP_MEMORY_SCOPE_AGENT);
        }
        *(float2*)&hS[pe0] = make_float2(__uint_as_float(((unsigned)(a >> 16) & 0xffffu) << 16),
                                         __uint_as_float(((unsigned)(a >> 32) & 0xffffu) << 16));
        *(float2*)&hS[pe0 + 544] = make_float2(__uint_as_float(((unsigned)(b >> 16) & 0xffffu) << 16),
                                               __uint_as_float(((unsigned)(b >> 32) & 0xffffu) << 16));
        __syncthreads();
        float a0 = 0.f, a1 = 0.f;
#pragma unroll
        for (int j = 0; j < 16; ++j) {
            const u32x4 w4 = wreg[j];
            const f32x4 h4 = hv4[j];
            a0 = fmaf(lo16f(w4.x), h4.x, a0); a1 = fmaf(hi16f(w4.x), h4.x, a1);
            a0 = fmaf(lo16f(w4.y), h4.y, a0); a1 = fmaf(hi16f(w4.y), h4.y, a1);
            a0 = fmaf(lo16f(w4.z), h4.z, a0); a1 = fmaf(hi16f(w4.z), h4.z, a1);
            a0 = fmaf(lo16f(w4.w), h4.w, a0); a1 = fmaf(hi16f(w4.w), h4.w, a1);
        }
        red[part * 33 + 2 * col2]     = a0;
        red[part * 33 + 2 * col2 + 1] = a1;
        __syncthreads();
        if (tid < RCOLS) {
            float s = 0.f;
#pragma unroll
            for (int p = 0; p < 16; ++p) s += red[p * 33 + tid];
            const float v = tanhf(xhS[t * RCOLS + tid] + s);
            const unsigned hb = (unsigned)bf16_bits(v);
            ((unsigned short*)hs)[(size_t)(c * NT + t) * HIDDEN + j0 + tid] = (unsigned short)hb;
            const unsigned pb = (unsigned)__shfl_xor((int)hb, 1, 64);
            if ((tid & 1) == 0) {
                const unsigned long long wv = (unsigned long long)(unsigned)(t + 1)
                                            | ((unsigned long long)hb << 16)
                                            | ((unsigned long long)pb << 32);
                __hip_atomic_store(&wbuf[m * 16 + (tid >> 1)], wv, __ATOMIC_RELAXED,
                                   __HIP_MEMORY_SCOPE_AGENT);
            }
        }
    }
}

// ---------------- y = hs @ Wt^T + b_y : 256x256, counted-vmcnt, 2-phase K-split ----------------
// Per K-tile: issue all 24 fragment ds_reads; lgkmcnt(12) -> MFMA ks0 overlaps ks1
// read drain; lgkmcnt(0) -> release barrier -> STAGE next (stays in flight, vmcnt(8))
// -> MFMA ks1 overlaps STAGE issue. Raw s_barrier only; setprio around MFMA clusters.
__global__ __launch_bounds__(512, 2) void k_proj(const unsigned short* __restrict__ A,   // [2048][1024]
                                                 const unsigned short* __restrict__ Bt,  // [32000][1024]
                                                 const float* __restrict__ by,
                                                 float* __restrict__ C) {
    __shared__ unsigned short LDS[4][16384];   // [buf*2+mat][256*64] bf16
    const int tid = threadIdx.x;
    const int wid = tid >> 6;
    const int lane = tid & 63;
    const int lin = blockIdx.x;
    const int swz = (lin & 7) * 125 + (lin >> 3);
    const int mt = swz & 7, nt = swz >> 3;
    const int m0 = mt * 256, n0 = nt * 256;
    const int wr = wid >> 2, wc = wid & 3;
    const int fr = lane & 15, fq = lane >> 4;
    const int srow = tid >> 3;
    const int sslot = tid & 7;

    f32x4 acc[8][4] = {};

#define STAGE(kt, bf)                                                                     \
    {                                                                                     \
        const unsigned short* Ag = A + (size_t)m0 * HIDDEN + (size_t)(kt) * 64;           \
        const unsigned short* Bg = Bt + (size_t)n0 * HIDDEN + (size_t)(kt) * 64;          \
        _Pragma("unroll")                                                                 \
        for (int j = 0; j < 4; ++j) {                                                     \
            const int r = j * 64 + srow;                                                  \
            const int ls = ((sslot ^ (r & 7)) * 8);                                       \
            __builtin_amdgcn_global_load_lds(                                             \
                (const AS1 unsigned*)(Ag + (size_t)r * HIDDEN + ls),                      \
                (AS3 unsigned*)(&LDS[(bf) * 2 + 0][j * 4096 + wid * 512]), 16, 0, 0);     \
        }                                                                                 \
        _Pragma("unroll")                                                                 \
        for (int j = 0; j < 4; ++j) {                                                     \
            const int r = j * 64 + srow;                                                  \
            const int ls = ((sslot ^ (r & 7)) * 8);                                       \
            __builtin_amdgcn_global_load_lds(                                             \
                (const AS1 unsigned*)(Bg + (size_t)r * HIDDEN + ls),                      \
                (AS3 unsigned*)(&LDS[(bf) * 2 + 1][j * 4096 + wid * 512]), 16, 0, 0);     \
        }                                                                                 \
    }

    STAGE(0, 0);
    STAGE(1, 1);

    int cur = 0;
    for (int kt = 0; kt < 16; ++kt) {
        if (kt < 15) { asm volatile("s_waitcnt vmcnt(8)" ::: "memory"); }
        else         { asm volatile("s_waitcnt vmcnt(0)" ::: "memory"); }
        __builtin_amdgcn_s_barrier();          // tile bf=cur visible to all waves

        const unsigned short* Ab = &LDS[cur * 2 + 0][0];
        const unsigned short* Bb = &LDS[cur * 2 + 1][0];
        bf16x8 af[8][2], bg[4][2];
        // ks0 fragment reads first (order biases the lgkmcnt(12) split)
#pragma unroll
        for (int mi = 0; mi < 8; ++mi) {
            const int ra = wr * 128 + mi * 16 + fr;
            af[mi][0] = *(const bf16x8*)&Ab[ra * 64 + (((0 * 4 + fq) ^ (fr & 7)) * 8)];
        }
#pragma unroll
        for (int ni = 0; ni < 4; ++ni) {
            const int rb = wc * 64 + ni * 16 + fr;
            bg[ni][0] = *(const bf16x8*)&Bb[rb * 64 + (((0 * 4 + fq) ^ (fr & 7)) * 8)];
        }
#pragma unroll
        for (int mi = 0; mi < 8; ++mi) {
            const int ra = wr * 128 + mi * 16 + fr;
            af[mi][1] = *(const bf16x8*)&Ab[ra * 64 + (((1 * 4 + fq) ^ (fr & 7)) * 8)];
        }
#pragma unroll
        for (int ni = 0; ni < 4; ++ni) {
            const int rb = wc * 64 + ni * 16 + fr;
            bg[ni][1] = *(const bf16x8*)&Bb[rb * 64 + (((1 * 4 + fq) ^ (fr & 7)) * 8)];
        }
        asm volatile("s_waitcnt lgkmcnt(12)" ::: "memory");
        __builtin_amdgcn_sched_barrier(0);
        __builtin_amdgcn_s_setprio(1);
#pragma unroll
        for (int mi = 0; mi < 8; ++mi)
#pragma unroll
            for (int ni = 0; ni < 4; ++ni)
                acc[mi][ni] = __builtin_amdgcn_mfma_f32_16x16x32_bf16(af[mi][0], bg[ni][0], acc[mi][ni], 0, 0, 0);
        __builtin_amdgcn_s_setprio(0);
        asm volatile("s_waitcnt lgkmcnt(0)" ::: "memory");
        __builtin_amdgcn_sched_barrier(0);
        __builtin_amdgcn_s_barrier();          // all waves done reading bf=cur

        if (kt < 14) STAGE(kt + 2, cur);       // refill freed buffer; stays in flight

        __builtin_amdgcn_s_setprio(1);
#pragma unroll
        for (int mi = 0; mi < 8; ++mi)
#pragma unroll
            for (int ni = 0; ni < 4; ++ni)
                acc[mi][ni] = __builtin_amdgcn_mfma_f32_16x16x32_bf16(af[mi][1], bg[ni][1], acc[mi][ni], 0, 0, 0);
        __builtin_amdgcn_s_setprio(0);
        cur ^= 1;
    }
#undef STAGE

#pragma unroll
    for (int ni = 0; ni < 4; ++ni) {
        const int col = n0 + wc * 64 + ni * 16 + fr;
        const float bias = by[col];
#pragma unroll
        for (int mi = 0; mi < 8; ++mi) {
            const int row = m0 + wr * 128 + mi * 16 + fq * 4;
            float* cp = C + (size_t)row * VOCAB + col;
            cp[0]                 = acc[mi][ni][0] + bias;
            cp[(size_t)VOCAB]     = acc[mi][ni][1] + bias;
            cp[(size_t)2 * VOCAB] = acc[mi][ni][2] + bias;
            cp[(size_t)3 * VOCAB] = acc[mi][ni][3] + bias;
        }
    }
}

extern "C" void kernel_launch(void* const* d_in, const int* in_sizes, int n_in,
                              void* d_out, int out_size, void* d_ws, size_t ws_size,
                              hipStream_t stream) {
    const int*   x   = (const int*)d_in[0];
    const float* emb = (const float*)d_in[1];
    const float* Wxh = (const float*)d_in[2];
    const float* Whh = (const float*)d_in[3];
    const float* bh  = (const float*)d_in[4];
    const float* Why = (const float*)d_in[5];
    const float* by  = (const float*)d_in[6];
    float* y = (float*)d_out;

    char* ws = (char*)d_ws;
    // layout: xh (8 MB) | hx u64[8][2][512] (64 KB) | hs bf16 (4 MB) | Wt bf16 (62.5 MB)
    const size_t off_xh = 0;
    const size_t off_hx = off_xh + (size_t)NB * NT * HIDDEN * 4;
    const size_t off_hs = off_hx + (size_t)NCH * 2 * 512 * 8;
    const size_t off_wt = off_hs + (size_t)NB * NT * HIDDEN * 2;
    const size_t need   = off_wt + (size_t)VOCAB * HIDDEN * 2;
    if (ws_size < need) return;

    float* xh = (float*)(ws + off_xh);
    unsigned long long* hx = (unsigned long long*)(ws + off_hx);
    __hip_bfloat16* hs = (__hip_bfloat16*)(ws + off_hs);
    __hip_bfloat16* Wt = (__hip_bfloat16*)(ws + off_wt);

    k_xh<<<dim3((NB * NT) / XH_ROWS), 256, 0, stream>>>(x, emb, Wxh, bh, xh);
    k_fused<<<dim3(NBLK_REC + NBLK_TR), 256, 0, stream>>>(Whh, xh, hx, hs, Why, Wt);
    k_proj<<<dim3((2048 / 256) * (VOCAB / 256)), 512, 0, stream>>>((const unsigned short*)hs,
                                                                   (const unsigned short*)Wt, by, y);
}